// Round 1
// baseline (402.283 us; speedup 1.0000x reference)
//
#include <hip/hip_runtime.h>

#define NH 8
#define CDIM 384
#define HDIM 48
#define NTOK 4096
#define PDIM 256
#define BDIM 4

typedef unsigned short u16;
typedef unsigned int u32;
typedef __bf16 bf16x8 __attribute__((ext_vector_type(8)));
typedef float f32x4 __attribute__((ext_vector_type(4)));

__device__ __forceinline__ u16 f2b(float f) {
    u32 u = __float_as_uint(f);
    u = (u + 0x7fffu + ((u >> 16) & 1u)) >> 16;   // RNE bf16
    return (u16)u;
}

__device__ __forceinline__ bf16x8 bzero8() {
    bf16x8 v;
#pragma unroll
    for (int i = 0; i < 8; i++) v[i] = (__bf16)0.0f;
    return v;
}

// ---------------------------------------------------------------------------
// Batched transpose + cast: in f32 [Z,R,Cc] -> outT bf16 [Z,Cc,R]
// optional outC bf16 [Z,R,Cc] (straight cast). block (32,8)
// ---------------------------------------------------------------------------
__global__ __launch_bounds__(256) void transpose_cast(
    const float* __restrict__ in, u16* __restrict__ outT, u16* __restrict__ outC,
    int R, int Cc)
{
    __shared__ float tile[32][33];
    int r0 = blockIdx.y * 32, c0 = blockIdx.x * 32;
    size_t zoff = (size_t)blockIdx.z * R * Cc;
    const float* inp = in + zoff;
    int tx = threadIdx.x, ty = threadIdx.y;
#pragma unroll
    for (int i = 0; i < 4; i++) {
        int r = r0 + ty + i * 8;
        float v = inp[(size_t)r * Cc + c0 + tx];
        tile[ty + i * 8][tx] = v;
        if (outC) outC[zoff + (size_t)r * Cc + c0 + tx] = f2b(v);
    }
    __syncthreads();
    u16* oT = outT + zoff;
#pragma unroll
    for (int i = 0; i < 4; i++) {
        int c = c0 + ty + i * 8;
        oT[(size_t)c * R + r0 + tx] = f2b(tile[tx][ty + i * 8]);
    }
}

// ---------------------------------------------------------------------------
// Generic GEMM: C[M,N] = A[M,K](bf16,row) @ Bt[N,K](bf16,row)^T, f32 accum.
// 128x128 tile, BK=32, 4 waves (2x2 of 64x64), 16x16x32 MFMA.
// EPI 0: f32 store to Cf (ldc=Nn, batch stride sC)
// EPI 1: gelu(x+bias) -> bf16 Cbf [M,Nn]
// EPI 2: x + bias[n] + Yin[b,n_col,tok] -> f32 Out[b,n_col,tok]  (b=m>>12, tok=m&4095)
// ---------------------------------------------------------------------------
template <int EPI>
__global__ __launch_bounds__(256) void gemm_bt(
    const u16* __restrict__ A, const u16* __restrict__ Bt,
    int M, int Nn, int K, long sA, long sB, long sC,
    float* __restrict__ Cf, const float* __restrict__ bias,
    u16* __restrict__ Cbf, const float* __restrict__ Yin, float* __restrict__ Out)
{
    const int BM = 128, BN = 128, BK = 32, LP = 40;
    __shared__ u16 lsA[128 * 40];
    __shared__ u16 lsB[128 * 40];
    const int tid = threadIdx.x;
    const int wave = tid >> 6, lane = tid & 63;
    const int lm = lane & 15, lkb = lane >> 4;
    const int bm = blockIdx.x, bn = blockIdx.y, bz = blockIdx.z;
    const u16* Ab = A + (size_t)bz * sA;
    const u16* Bb = Bt + (size_t)bz * sB;
    const int wm = (wave >> 1) * 64, wn = (wave & 1) * 64;

    f32x4 acc[4][4];
#pragma unroll
    for (int i = 0; i < 4; i++)
#pragma unroll
        for (int j = 0; j < 4; j++) acc[i][j] = f32x4{0.f, 0.f, 0.f, 0.f};

    for (int k0 = 0; k0 < K; k0 += BK) {
#pragma unroll
        for (int i = 0; i < 2; i++) {
            int id = tid + i * 256;
            int r = id >> 2, ch = id & 3;
            uint4 va = *(const uint4*)(Ab + (size_t)(bm * BM + r) * K + k0 + ch * 8);
            uint4 vb = *(const uint4*)(Bb + (size_t)(bn * BN + r) * K + k0 + ch * 8);
            *(uint4*)&lsA[r * LP + ch * 8] = va;
            *(uint4*)&lsB[r * LP + ch * 8] = vb;
        }
        __syncthreads();
        bf16x8 af[4], bfr[4];
#pragma unroll
        for (int t = 0; t < 4; t++) {
            af[t]  = *(const bf16x8*)&lsA[(wm + t * 16 + lm) * LP + lkb * 8];
            bfr[t] = *(const bf16x8*)&lsB[(wn + t * 16 + lm) * LP + lkb * 8];
        }
#pragma unroll
        for (int mi = 0; mi < 4; mi++)
#pragma unroll
            for (int ni = 0; ni < 4; ni++)
                acc[mi][ni] = __builtin_amdgcn_mfma_f32_16x16x32_bf16(
                    af[mi], bfr[ni], acc[mi][ni], 0, 0, 0);
        __syncthreads();
    }

#pragma unroll
    for (int mi = 0; mi < 4; mi++)
#pragma unroll
        for (int ni = 0; ni < 4; ni++)
#pragma unroll
            for (int r = 0; r < 4; r++) {
                int m = bm * BM + wm + mi * 16 + lkb * 4 + r;
                int n = bn * BN + wn + ni * 16 + lm;
                float v = acc[mi][ni][r];
                if (EPI == 0) {
                    Cf[(size_t)bz * sC + (size_t)m * Nn + n] = v;
                } else if (EPI == 1) {
                    float x = v + bias[n];
                    float g = 0.5f * x * (1.0f + erff(x * 0.70710678118654752f));
                    Cbf[(size_t)m * Nn + n] = f2b(g);
                } else {
                    int b = m >> 12, tok = m & 4095;
                    size_t oi = ((size_t)b * CDIM + n) * NTOK + tok;
                    Out[oi] = v + bias[n] + Yin[oi];
                }
            }
}

// ---------------------------------------------------------------------------
// Column sum-of-squares of q [B,N,C] over N (partial over 256-token chunks)
// ---------------------------------------------------------------------------
__global__ __launch_bounds__(128) void colsumsq(
    const float* __restrict__ q, float* __restrict__ pcs)
{
    int c = blockIdx.x * 128 + threadIdx.x;
    int b = blockIdx.z;
    int chunk = blockIdx.y;
    const float* qp = q + ((size_t)b * NTOK + chunk * 256) * CDIM + c;
    float s = 0.f;
#pragma unroll 4
    for (int i = 0; i < 256; i++) { float v = qp[(size_t)i * CDIM]; s += v * v; }
    pcs[(size_t)chunk * (BDIM * CDIM) + b * CDIM + c] = s;
}

__global__ __launch_bounds__(256) void colsumred(
    const float* __restrict__ pcs, float* __restrict__ css)
{
    int idx = blockIdx.x * 256 + threadIdx.x;
    if (idx < BDIM * CDIM) {
        float s = 0.f;
#pragma unroll
        for (int j = 0; j < 16; j++) s += pcs[(size_t)j * (BDIM * CDIM) + idx];
        css[idx] = s;
    }
}

// ---------------------------------------------------------------------------
// kp/vp: kp[b,c,p] = sum_c' Wkv[c',c] * G[b,c',p];  vp uses Wkv[c', C+c]
// ---------------------------------------------------------------------------
__global__ __launch_bounds__(256) void kpvp_kernel(
    const float* __restrict__ Wkv, const float* __restrict__ G,
    float* __restrict__ kp, float* __restrict__ vp)
{
    int c = blockIdx.x, b = blockIdx.y, p = threadIdx.x;
    const float* Gb = G + (size_t)b * CDIM * PDIM + p;
    float ak = 0.f, av = 0.f;
    for (int cp = 0; cp < CDIM; cp++) {
        float g = Gb[(size_t)cp * PDIM];
        ak += Wkv[(size_t)cp * (2 * CDIM) + c] * g;
        av += Wkv[(size_t)cp * (2 * CDIM) + CDIM + c] * g;
    }
    kp[((size_t)b * CDIM + c) * PDIM + p] = ak;
    vp[((size_t)b * CDIM + c) * PDIM + p] = av;
}

// ---------------------------------------------------------------------------
// Scale kp by temp[h]/max(||q_col||,eps), pack to bf16:
// kps [b,h,p,d]  (Bt layout for QK^T);  vpb [b,h,d,p] (Bt layout for PV)
// ---------------------------------------------------------------------------
__global__ __launch_bounds__(256) void scalepack(
    const float* __restrict__ kp, const float* __restrict__ vp,
    const float* __restrict__ css, const float* __restrict__ temp,
    u16* __restrict__ kps, u16* __restrict__ vpb)
{
    int idx = blockIdx.x * 256 + threadIdx.x;  // (b,h,d,p), p fastest
    int p = idx & 255;
    int r = idx >> 8;
    int d = r % HDIM;
    int bh = r / HDIM;
    int h = bh & 7;
    int b = bh >> 3;
    int c = h * HDIM + d;
    float nrm = fmaxf(sqrtf(css[b * CDIM + c]), 1e-12f);
    float sc = temp[h] / nrm;
    size_t src = ((size_t)b * CDIM + c) * PDIM + p;
    kps[((size_t)bh * PDIM + p) * HDIM + d] = f2b(kp[src] * sc);
    vpb[((size_t)bh * HDIM + d) * PDIM + p] = f2b(vp[src]);
}

// ---------------------------------------------------------------------------
// f32 -> bf16 elementwise (4 per thread)
// ---------------------------------------------------------------------------
__global__ __launch_bounds__(256) void castbf(
    const float* __restrict__ in, u16* __restrict__ out, size_t n)
{
    size_t i = ((size_t)blockIdx.x * 256 + threadIdx.x) * 4;
    if (i < n) {
        float4 v = *(const float4*)(in + i);
        ushort4 o;
        o.x = f2b(v.x); o.y = f2b(v.y); o.z = f2b(v.z); o.w = f2b(v.w);
        *(ushort4*)(out + i) = o;
    }
}

// ---------------------------------------------------------------------------
// Fused attention: per (ntile of 64 tokens, h, b).
// s = q_bf[.,hslice] @ kps^T (K=48), softmax over P=256 in-register,
// o = p @ vpb^T (K=256). Output scatter to scrambled layout (d*8+h)*4096+n.
// ---------------------------------------------------------------------------
__global__ __launch_bounds__(256) void attn_fused(
    const u16* __restrict__ qbf, const u16* __restrict__ kps,
    const u16* __restrict__ vpb, float* __restrict__ o_scr)
{
    __shared__ u16 kp_l[256 * 56];   // [p][d] pad 48->56
    __shared__ u16 vp_l[48 * 264];   // [d][p] pad 256->264
    __shared__ u16 p_l[64 * 264];    // [tok][p] pad

    int nt = blockIdx.x, h = blockIdx.y, b = blockIdx.z;
    int tid = threadIdx.x, wave = tid >> 6, lane = tid & 63;
    int lm = lane & 15, lkb = lane >> 4;
    const u16* kpsb = kps + (size_t)(b * NH + h) * PDIM * HDIM;
    const u16* vpbb = vpb + (size_t)(b * NH + h) * HDIM * PDIM;

    for (int i = tid; i < 1536; i += 256) {      // 256 rows x 6 uint4
        int row = i / 6, ch = i % 6;
        *(uint4*)&kp_l[row * 56 + ch * 8] = *(const uint4*)(kpsb + row * 48 + ch * 8);
    }
    for (int i = tid; i < 1536; i += 256) {      // 48 rows x 32 uint4
        int row = i / 32, ch = i % 32;
        *(uint4*)&vp_l[row * 264 + ch * 8] = *(const uint4*)(vpbb + row * 256 + ch * 8);
    }
    __syncthreads();

    int t0 = nt * 64 + wave * 16;
    const u16* qb = qbf + ((size_t)b * NTOK + t0 + lm) * CDIM + h * HDIM;
    bf16x8 a0 = *(const bf16x8*)(qb + lkb * 8);
    bf16x8 a1 = bzero8();
    if (lkb < 2) a1 = *(const bf16x8*)(qb + 32 + lkb * 8);

    f32x4 s[16];
#pragma unroll
    for (int pi = 0; pi < 16; pi++) {
        f32x4 acc = f32x4{0.f, 0.f, 0.f, 0.f};
        bf16x8 b0 = *(const bf16x8*)&kp_l[(pi * 16 + lm) * 56 + lkb * 8];
        acc = __builtin_amdgcn_mfma_f32_16x16x32_bf16(a0, b0, acc, 0, 0, 0);
        bf16x8 b1 = bzero8();
        if (lkb < 2) b1 = *(const bf16x8*)&kp_l[(pi * 16 + lm) * 56 + 32 + lkb * 8];
        acc = __builtin_amdgcn_mfma_f32_16x16x32_bf16(a1, b1, acc, 0, 0, 0);
        s[pi] = acc;
    }

    // softmax over 256 cols: values for token (lkb*4+r) live in 16 tiles x 16 lanes
#pragma unroll
    for (int r = 0; r < 4; r++) {
        float mx = s[0][r];
#pragma unroll
        for (int pi = 1; pi < 16; pi++) mx = fmaxf(mx, s[pi][r]);
        for (int m = 1; m < 16; m <<= 1) mx = fmaxf(mx, __shfl_xor(mx, m, 64));
        float e[16];
        float sum = 0.f;
#pragma unroll
        for (int pi = 0; pi < 16; pi++) { e[pi] = __expf(s[pi][r] - mx); sum += e[pi]; }
        for (int m = 1; m < 16; m <<= 1) sum += __shfl_xor(sum, m, 64);
        float inv = 1.0f / sum;
        int tl = wave * 16 + lkb * 4 + r;
#pragma unroll
        for (int pi = 0; pi < 16; pi++)
            p_l[tl * 264 + pi * 16 + lm] = f2b(e[pi] * inv);
    }
    __syncthreads();

    // o = p @ vp^T : per wave 16 tokens x 48 d, K=256
    f32x4 oa[3];
#pragma unroll
    for (int di = 0; di < 3; di++) oa[di] = f32x4{0.f, 0.f, 0.f, 0.f};
#pragma unroll
    for (int ks = 0; ks < 8; ks++) {
        bf16x8 pa = *(const bf16x8*)&p_l[(wave * 16 + lm) * 264 + ks * 32 + lkb * 8];
#pragma unroll
        for (int di = 0; di < 3; di++) {
            bf16x8 vb = *(const bf16x8*)&vp_l[(di * 16 + lm) * 264 + ks * 32 + lkb * 8];
            oa[di] = __builtin_amdgcn_mfma_f32_16x16x32_bf16(pa, vb, oa[di], 0, 0, 0);
        }
    }
    size_t obase = (size_t)b * ((size_t)NTOK * CDIM);
#pragma unroll
    for (int di = 0; di < 3; di++)
#pragma unroll
        for (int r = 0; r < 4; r++) {
            int n = t0 + lkb * 4 + r;
            int d = di * 16 + lm;
            o_scr[obase + ((size_t)(d * NH + h)) * NTOK + n] = oa[di][r];
        }
}

// ---------------------------------------------------------------------------
// LayerNorm over rows of 384, write bf16. block 128, one row per block.
// ---------------------------------------------------------------------------
__global__ __launch_bounds__(128) void ln_kernel(
    const float* __restrict__ o, const float* __restrict__ gamma,
    const float* __restrict__ beta, u16* __restrict__ outbf)
{
    int row = blockIdx.x;
    const float* rp = o + (size_t)row * CDIM;
    int tid = threadIdx.x;
    float v0 = rp[tid], v1 = rp[tid + 128], v2 = rp[tid + 256];
    float s = v0 + v1 + v2;
    for (int m = 1; m < 64; m <<= 1) s += __shfl_xor(s, m, 64);
    __shared__ float red[2];
    if ((tid & 63) == 0) red[tid >> 6] = s;
    __syncthreads();
    float mean = (red[0] + red[1]) * (1.0f / CDIM);
    float d0 = v0 - mean, d1 = v1 - mean, d2 = v2 - mean;
    float qv = d0 * d0 + d1 * d1 + d2 * d2;
    for (int m = 1; m < 64; m <<= 1) qv += __shfl_xor(qv, m, 64);
    __shared__ float red2[2];
    if ((tid & 63) == 0) red2[tid >> 6] = qv;
    __syncthreads();
    float var = (red2[0] + red2[1]) * (1.0f / CDIM);
    float rstd = rsqrtf(var + 1e-5f);
    u16* op = outbf + (size_t)row * CDIM;
    op[tid]       = f2b(d0 * rstd * gamma[tid]       + beta[tid]);
    op[tid + 128] = f2b(d1 * rstd * gamma[tid + 128] + beta[tid + 128]);
    op[tid + 256] = f2b(d2 * rstd * gamma[tid + 256] + beta[tid + 256]);
}

// ---------------------------------------------------------------------------
extern "C" void kernel_launch(void* const* d_in, const int* in_sizes, int n_in,
                              void* d_out, int out_size, void* d_ws, size_t ws_size,
                              hipStream_t stream)
{
    (void)in_sizes; (void)n_in; (void)out_size; (void)ws_size;
    const float* x    = (const float*)d_in[0];
    const float* y    = (const float*)d_in[1];
    const float* Wq   = (const float*)d_in[2];
    const float* Wkv  = (const float*)d_in[3];
    const float* EF   = (const float*)d_in[4];
    const float* temp = (const float*)d_in[5];
    const float* gam  = (const float*)d_in[6];
    const float* bet  = (const float*)d_in[7];
    const float* w1   = (const float*)d_in[8];
    const float* b1   = (const float*)d_in[9];
    const float* w2   = (const float*)d_in[10];
    const float* b2   = (const float*)d_in[11];
    float* out = (float*)d_out;

    char* w = (char*)d_ws;
    size_t off = 0;
    auto alloc = [&](size_t nb) { size_t o = off; off += (nb + 255) & ~(size_t)255; return o; };
    u16*   xt_bf = (u16*)(w + alloc((size_t)BDIM * NTOK * CDIM * 2)); // reused as q_bf
    u16*   x_bf  = (u16*)(w + alloc((size_t)BDIM * NTOK * CDIM * 2)); // reused as ln_bf
    u16*   Wqt   = (u16*)(w + alloc((size_t)CDIM * CDIM * 2));
    u16*   EFt   = (u16*)(w + alloc((size_t)PDIM * NTOK * 2));
    u16*   w1t   = (u16*)(w + alloc((size_t)1536 * CDIM * 2));
    u16*   w2t   = (u16*)(w + alloc((size_t)CDIM * 1536 * 2));
    float* qf    = (float*)(w + alloc((size_t)BDIM * NTOK * CDIM * 4)); // reused as o_scr
    float* Gf    = (float*)(w + alloc((size_t)BDIM * CDIM * PDIM * 4));
    float* kpf   = (float*)(w + alloc((size_t)BDIM * CDIM * PDIM * 4));
    float* vpf   = (float*)(w + alloc((size_t)BDIM * CDIM * PDIM * 4));
    float* pcs   = (float*)(w + alloc((size_t)16 * BDIM * CDIM * 4));
    float* css   = (float*)(w + alloc((size_t)BDIM * CDIM * 4));
    u16*   kps   = (u16*)(w + alloc((size_t)BDIM * NH * PDIM * HDIM * 2));
    u16*   vpb   = (u16*)(w + alloc((size_t)BDIM * NH * HDIM * PDIM * 2));
    u16*   h1bf  = (u16*)(w + alloc((size_t)BDIM * NTOK * 1536 * 2));
    u16*   q_bf  = xt_bf;
    float* o_scr = qf;
    u16*   ln_bf = x_bf;

    dim3 tb(32, 8, 1);
    // x [B,C,N] -> xt_bf [B,N,C] + x_bf [B,C,N]
    transpose_cast<<<dim3(NTOK / 32, CDIM / 32, BDIM), tb, 0, stream>>>(x, xt_bf, x_bf, CDIM, NTOK);
    transpose_cast<<<dim3(CDIM / 32, CDIM / 32, 1), tb, 0, stream>>>(Wq, Wqt, nullptr, CDIM, CDIM);
    transpose_cast<<<dim3(PDIM / 32, NTOK / 32, 1), tb, 0, stream>>>(EF, EFt, nullptr, NTOK, PDIM);
    transpose_cast<<<dim3(1536 / 32, CDIM / 32, 1), tb, 0, stream>>>(w1, w1t, nullptr, CDIM, 1536);
    transpose_cast<<<dim3(CDIM / 32, 1536 / 32, 1), tb, 0, stream>>>(w2, w2t, nullptr, 1536, CDIM);

    // q = xt @ Wq  -> f32 [B,N,C]
    gemm_bt<0><<<dim3(NTOK / 128, CDIM / 128, BDIM), 256, 0, stream>>>(
        xt_bf, Wqt, NTOK, CDIM, CDIM, (long)NTOK * CDIM, 0, (long)NTOK * CDIM,
        qf, nullptr, nullptr, nullptr, nullptr);
    // G = x @ EF -> f32 [B,C,P]
    gemm_bt<0><<<dim3(CDIM / 128, PDIM / 128, BDIM), 256, 0, stream>>>(
        x_bf, EFt, CDIM, PDIM, NTOK, (long)CDIM * NTOK, 0, (long)CDIM * PDIM,
        Gf, nullptr, nullptr, nullptr, nullptr);

    colsumsq<<<dim3(CDIM / 128, 16, BDIM), 128, 0, stream>>>(qf, pcs);
    colsumred<<<dim3(6, 1, 1), 256, 0, stream>>>(pcs, css);
    kpvp_kernel<<<dim3(CDIM, BDIM, 1), 256, 0, stream>>>(Wkv, Gf, kpf, vpf);
    scalepack<<<dim3((BDIM * NH * HDIM * PDIM) / 256, 1, 1), 256, 0, stream>>>(
        kpf, vpf, css, temp, kps, vpb);
    castbf<<<dim3((BDIM * NTOK * CDIM) / 1024, 1, 1), 256, 0, stream>>>(
        qf, q_bf, (size_t)BDIM * NTOK * CDIM);

    attn_fused<<<dim3(NTOK / 64, NH, BDIM), 256, 0, stream>>>(q_bf, kps, vpb, o_scr);

    ln_kernel<<<dim3(BDIM * NTOK, 1, 1), 128, 0, stream>>>(o_scr, gam, bet, ln_bf);

    // MLP1: gelu(ln @ w1 + b1) -> bf16 [16384,1536]
    gemm_bt<1><<<dim3((BDIM * NTOK) / 128, 1536 / 128, 1), 256, 0, stream>>>(
        ln_bf, w1t, BDIM * NTOK, 1536, CDIM, 0, 0, 0,
        nullptr, b1, h1bf, nullptr, nullptr);
    // MLP2: h1 @ w2 + b2 + y (transposed add) -> f32 out [B,C,N]
    gemm_bt<2><<<dim3((BDIM * NTOK) / 128, CDIM / 128, 1), 256, 0, stream>>>(
        h1bf, w2t, BDIM * NTOK, CDIM, 1536, 0, 0, 0,
        nullptr, b2, nullptr, y, out);
}

// Round 2
// 236.709 us; speedup vs baseline: 1.6995x; 1.6995x over previous
//
#include <hip/hip_runtime.h>

#define NH 8
#define CDIM 384
#define HDIM 48
#define NTOK 4096
#define PDIM 256
#define BDIM 4

typedef unsigned short u16;
typedef unsigned int u32;
typedef __bf16 bf16x8 __attribute__((ext_vector_type(8)));
typedef float f32x4 __attribute__((ext_vector_type(4)));

__device__ __forceinline__ u16 f2b(float f) {
    u32 u = __float_as_uint(f);
    u = (u + 0x7fffu + ((u >> 16) & 1u)) >> 16;   // RNE bf16
    return (u16)u;
}

__device__ __forceinline__ bf16x8 bzero8() {
    bf16x8 v;
#pragma unroll
    for (int i = 0; i < 8; i++) v[i] = (__bf16)0.0f;
    return v;
}

__device__ __forceinline__ void gload16(const u16* g, u16* l) {
    __builtin_amdgcn_global_load_lds(
        (const __attribute__((address_space(1))) void*)g,
        (__attribute__((address_space(3))) void*)l, 16, 0, 0);
}

// ---------------------------------------------------------------------------
// Batched transpose + cast: in f32 [Z,R,Cc] -> outT bf16 [Z,Cc,R]
// optional outC bf16 [Z,R,Cc] (straight cast). block (32,8)
// ---------------------------------------------------------------------------
__global__ __launch_bounds__(256) void transpose_cast(
    const float* __restrict__ in, u16* __restrict__ outT, u16* __restrict__ outC,
    int R, int Cc)
{
    __shared__ float tile[32][33];
    int r0 = blockIdx.y * 32, c0 = blockIdx.x * 32;
    size_t zoff = (size_t)blockIdx.z * R * Cc;
    const float* inp = in + zoff;
    int tx = threadIdx.x, ty = threadIdx.y;
#pragma unroll
    for (int i = 0; i < 4; i++) {
        int r = r0 + ty + i * 8;
        float v = inp[(size_t)r * Cc + c0 + tx];
        tile[ty + i * 8][tx] = v;
        if (outC) outC[zoff + (size_t)r * Cc + c0 + tx] = f2b(v);
    }
    __syncthreads();
    u16* oT = outT + zoff;
#pragma unroll
    for (int i = 0; i < 4; i++) {
        int c = c0 + ty + i * 8;
        oT[(size_t)c * R + r0 + tx] = f2b(tile[tx][ty + i * 8]);
    }
}

// ---------------------------------------------------------------------------
// Generic GEMM: C[M,N] = A[M,K](bf16,row) @ Bt[N,K](bf16,row)^T, f32 accum.
// 128x128 tile, BK=32, 4 waves (2x2 of 64x64), 16x16x32 MFMA.
// Staging via global_load_lds width=16, linear LDS (LP=32).
// EPI 0: f32 store to Cf
// EPI 1: gelu(x+bias) -> bf16 Cbf [M,Nn]
// EPI 2: x + bias[n] + Yin[b,n,tok] -> f32 Out[b,n,tok]  (b=m>>12, tok=m&4095)
// EPI 3: f32 store to Cf AND bf16 store to Cbf (same layout)
// EPI 4: split-K partials: bz = b*16+s, K-chunk s of 16, store f32 slice bz
// ---------------------------------------------------------------------------
template <int EPI>
__global__ __launch_bounds__(256) void gemm_bt(
    const u16* __restrict__ A, const u16* __restrict__ Bt,
    int M, int Nn, int K, long sA, long sB, long sC,
    float* __restrict__ Cf, const float* __restrict__ bias,
    u16* __restrict__ Cbf, const float* __restrict__ Yin, float* __restrict__ Out)
{
    const int BM = 128, BK = 32, LP = 32;
    __shared__ u16 lsA[128 * LP];
    __shared__ u16 lsB[128 * LP];
    const int tid = threadIdx.x;
    const int wave = tid >> 6, lane = tid & 63;
    const int lm = lane & 15, lkb = lane >> 4;
    const int bm = blockIdx.x, bn = blockIdx.y, bz = blockIdx.z;
    int bb = bz, ks = 0, ke = K;
    if (EPI == 4) { bb = bz >> 4; ks = (bz & 15) * (K >> 4); ke = ks + (K >> 4); }
    const u16* Ab = A + (size_t)bb * sA;
    const u16* Bb = Bt + (size_t)bb * sB;
    const int wm = (wave >> 1) * 64, wn = (wave & 1) * 64;

    f32x4 acc[4][4];
#pragma unroll
    for (int i = 0; i < 4; i++)
#pragma unroll
        for (int j = 0; j < 4; j++) acc[i][j] = f32x4{0.f, 0.f, 0.f, 0.f};

    for (int k0 = ks; k0 < ke; k0 += BK) {
#pragma unroll
        for (int j = 0; j < 2; j++) {
            int cb = (j * 4 + wave) * 64;            // 16B-chunk base, per-wave uniform
            int q = cb + lane;
            int r = q >> 2, ch = q & 3;
            gload16(Ab + (size_t)(bm * BM + r) * K + k0 + ch * 8, &lsA[cb * 8]);
            gload16(Bb + (size_t)(bn * BM + r) * K + k0 + ch * 8, &lsB[cb * 8]);
        }
        __syncthreads();
        bf16x8 af[4], bfr[4];
#pragma unroll
        for (int t = 0; t < 4; t++) {
            af[t]  = *(const bf16x8*)&lsA[(wm + t * 16 + lm) * LP + lkb * 8];
            bfr[t] = *(const bf16x8*)&lsB[(wn + t * 16 + lm) * LP + lkb * 8];
        }
#pragma unroll
        for (int mi = 0; mi < 4; mi++)
#pragma unroll
            for (int ni = 0; ni < 4; ni++)
                acc[mi][ni] = __builtin_amdgcn_mfma_f32_16x16x32_bf16(
                    af[mi], bfr[ni], acc[mi][ni], 0, 0, 0);
        __syncthreads();
    }

#pragma unroll
    for (int mi = 0; mi < 4; mi++)
#pragma unroll
        for (int ni = 0; ni < 4; ni++)
#pragma unroll
            for (int r = 0; r < 4; r++) {
                int m = bm * BM + wm + mi * 16 + lkb * 4 + r;
                int n = bn * BM + wn + ni * 16 + lm;
                float v = acc[mi][ni][r];
                if (EPI == 0) {
                    Cf[(size_t)bz * sC + (size_t)m * Nn + n] = v;
                } else if (EPI == 1) {
                    float x = v + bias[n];
                    float g = 0.5f * x * (1.0f + erff(x * 0.70710678118654752f));
                    Cbf[(size_t)m * Nn + n] = f2b(g);
                } else if (EPI == 2) {
                    int b = m >> 12, tok = m & 4095;
                    size_t oi = ((size_t)b * CDIM + n) * NTOK + tok;
                    Out[oi] = v + bias[n] + Yin[oi];
                } else if (EPI == 3) {
                    size_t oi = (size_t)bz * sC + (size_t)m * Nn + n;
                    Cf[oi] = v;
                    Cbf[oi] = f2b(v);
                } else {  // EPI == 4
                    Cf[(size_t)bz * sC + (size_t)m * Nn + n] = v;
                }
            }
}

// ---------------------------------------------------------------------------
// Reduce 16 split-K slices -> bf16 Gt [B, 256, 384]
// ---------------------------------------------------------------------------
__global__ __launch_bounds__(256) void gred(
    const float* __restrict__ part, u16* __restrict__ Gtb)
{
    int idx = blockIdx.x * 256 + threadIdx.x;      // over B*P*C
    int b = idx / (PDIM * CDIM);
    int e = idx % (PDIM * CDIM);
    float s = 0.f;
#pragma unroll
    for (int j = 0; j < 16; j++)
        s += part[((size_t)(b * 16 + j)) * (PDIM * CDIM) + e];
    Gtb[idx] = f2b(s);
}

// ---------------------------------------------------------------------------
// Column sum-of-squares of q [B,N,C] over N (partial over 256-token chunks)
// ---------------------------------------------------------------------------
__global__ __launch_bounds__(128) void colsumsq(
    const float* __restrict__ q, float* __restrict__ pcs)
{
    int c = blockIdx.x * 128 + threadIdx.x;
    int b = blockIdx.z;
    int chunk = blockIdx.y;
    const float* qp = q + ((size_t)b * NTOK + chunk * 256) * CDIM + c;
    float s = 0.f;
#pragma unroll 4
    for (int i = 0; i < 256; i++) { float v = qp[(size_t)i * CDIM]; s += v * v; }
    pcs[(size_t)chunk * (BDIM * CDIM) + b * CDIM + c] = s;
}

__global__ __launch_bounds__(256) void colsumred(
    const float* __restrict__ pcs, float* __restrict__ css)
{
    int idx = blockIdx.x * 256 + threadIdx.x;
    if (idx < BDIM * CDIM) {
        float s = 0.f;
#pragma unroll
        for (int j = 0; j < 16; j++) s += pcs[(size_t)j * (BDIM * CDIM) + idx];
        css[idx] = s;
    }
}

// ---------------------------------------------------------------------------
// From kpvp_t [b, p, 0:384]=kp, [b, p, 384:768]=vp (f32):
// kps [bh, p, d] scaled bf16;  vpb [bh, d, p] bf16
// idx over (b, p, c) with c fastest -> coalesced reads
// ---------------------------------------------------------------------------
__global__ __launch_bounds__(256) void scalepack2(
    const float* __restrict__ kpvp, const float* __restrict__ css,
    const float* __restrict__ temp, u16* __restrict__ kps, u16* __restrict__ vpb)
{
    int idx = blockIdx.x * 256 + threadIdx.x;      // over B*P*C
    int c = idx % CDIM;
    int t = idx / CDIM;
    int p = t & 255;
    int b = t >> 8;
    int h = c / HDIM, d = c % HDIM;
    const float* row = kpvp + ((size_t)b * PDIM + p) * (2 * CDIM);
    float kv = row[c];
    float vv = row[CDIM + c];
    float nrm = fmaxf(sqrtf(css[b * CDIM + c]), 1e-12f);
    float sc = temp[h] / nrm;
    int bh = b * NH + h;
    kps[((size_t)bh * PDIM + p) * HDIM + d] = f2b(kv * sc);
    vpb[((size_t)bh * HDIM + d) * PDIM + p] = f2b(vv);
}

// ---------------------------------------------------------------------------
// Fused attention: per (ntile of 64 tokens, h, b).
// ---------------------------------------------------------------------------
__global__ __launch_bounds__(256) void attn_fused(
    const u16* __restrict__ qbf, const u16* __restrict__ kps,
    const u16* __restrict__ vpb, float* __restrict__ o_scr)
{
    __shared__ u16 vp_l[48 * 264];   // [d][p] pad 256->264
    __shared__ u16 un[64 * 264];     // union: kp_l [256][56] then p_l [64][264]
    u16* kp_l = un;
    u16* p_l = un;

    int nt = blockIdx.x, h = blockIdx.y, b = blockIdx.z;
    int tid = threadIdx.x, wave = tid >> 6, lane = tid & 63;
    int lm = lane & 15, lkb = lane >> 4;
    const u16* kpsb = kps + (size_t)(b * NH + h) * PDIM * HDIM;
    const u16* vpbb = vpb + (size_t)(b * NH + h) * HDIM * PDIM;

    for (int i = tid; i < 1536; i += 256) {      // 256 rows x 6 uint4
        int row = i / 6, ch = i % 6;
        *(uint4*)&kp_l[row * 56 + ch * 8] = *(const uint4*)(kpsb + row * 48 + ch * 8);
    }
    for (int i = tid; i < 1536; i += 256) {      // 48 rows x 32 uint4
        int row = i / 32, ch = i % 32;
        *(uint4*)&vp_l[row * 264 + ch * 8] = *(const uint4*)(vpbb + row * 256 + ch * 8);
    }
    __syncthreads();

    int t0 = nt * 64 + wave * 16;
    const u16* qb = qbf + ((size_t)b * NTOK + t0 + lm) * CDIM + h * HDIM;
    bf16x8 a0 = *(const bf16x8*)(qb + lkb * 8);
    bf16x8 a1 = bzero8();
    if (lkb < 2) a1 = *(const bf16x8*)(qb + 32 + lkb * 8);

    f32x4 s[16];
#pragma unroll
    for (int pi = 0; pi < 16; pi++) {
        f32x4 acc = f32x4{0.f, 0.f, 0.f, 0.f};
        bf16x8 b0 = *(const bf16x8*)&kp_l[(pi * 16 + lm) * 56 + lkb * 8];
        acc = __builtin_amdgcn_mfma_f32_16x16x32_bf16(a0, b0, acc, 0, 0, 0);
        bf16x8 b1 = bzero8();
        if (lkb < 2) b1 = *(const bf16x8*)&kp_l[(pi * 16 + lm) * 56 + 32 + lkb * 8];
        acc = __builtin_amdgcn_mfma_f32_16x16x32_bf16(a1, b1, acc, 0, 0, 0);
        s[pi] = acc;
    }
    __syncthreads();   // all QK^T reads of kp_l done before p_l overwrites it

    // softmax over 256 cols; token (lkb*4+r) values live across 16 lanes x 16 tiles
#pragma unroll
    for (int r = 0; r < 4; r++) {
        float mx = s[0][r];
#pragma unroll
        for (int pi = 1; pi < 16; pi++) mx = fmaxf(mx, s[pi][r]);
        for (int m = 1; m < 16; m <<= 1) mx = fmaxf(mx, __shfl_xor(mx, m, 64));
        float e[16];
        float sum = 0.f;
#pragma unroll
        for (int pi = 0; pi < 16; pi++) { e[pi] = __expf(s[pi][r] - mx); sum += e[pi]; }
        for (int m = 1; m < 16; m <<= 1) sum += __shfl_xor(sum, m, 64);
        float inv = 1.0f / sum;
        int tl = wave * 16 + lkb * 4 + r;
#pragma unroll
        for (int pi = 0; pi < 16; pi++)
            p_l[tl * 264 + pi * 16 + lm] = f2b(e[pi] * inv);
    }
    __syncthreads();

    // o = p @ vp^T : per wave 16 tokens x 48 d, K=256
    f32x4 oa[3];
#pragma unroll
    for (int di = 0; di < 3; di++) oa[di] = f32x4{0.f, 0.f, 0.f, 0.f};
#pragma unroll
    for (int ksl = 0; ksl < 8; ksl++) {
        bf16x8 pa = *(const bf16x8*)&p_l[(wave * 16 + lm) * 264 + ksl * 32 + lkb * 8];
#pragma unroll
        for (int di = 0; di < 3; di++) {
            bf16x8 vb = *(const bf16x8*)&vp_l[(di * 16 + lm) * 264 + ksl * 32 + lkb * 8];
            oa[di] = __builtin_amdgcn_mfma_f32_16x16x32_bf16(pa, vb, oa[di], 0, 0, 0);
        }
    }
    size_t obase = (size_t)b * ((size_t)NTOK * CDIM);
#pragma unroll
    for (int di = 0; di < 3; di++)
#pragma unroll
        for (int r = 0; r < 4; r++) {
            int n = t0 + lkb * 4 + r;
            int d = di * 16 + lm;
            o_scr[obase + ((size_t)(d * NH + h)) * NTOK + n] = oa[di][r];
        }
}

// ---------------------------------------------------------------------------
// LayerNorm over rows of 384, write bf16. block 128, one row per block.
// ---------------------------------------------------------------------------
__global__ __launch_bounds__(128) void ln_kernel(
    const float* __restrict__ o, const float* __restrict__ gamma,
    const float* __restrict__ beta, u16* __restrict__ outbf)
{
    int row = blockIdx.x;
    const float* rp = o + (size_t)row * CDIM;
    int tid = threadIdx.x;
    float v0 = rp[tid], v1 = rp[tid + 128], v2 = rp[tid + 256];
    float s = v0 + v1 + v2;
    for (int m = 1; m < 64; m <<= 1) s += __shfl_xor(s, m, 64);
    __shared__ float red[2];
    if ((tid & 63) == 0) red[tid >> 6] = s;
    __syncthreads();
    float mean = (red[0] + red[1]) * (1.0f / CDIM);
    float d0 = v0 - mean, d1 = v1 - mean, d2 = v2 - mean;
    float qv = d0 * d0 + d1 * d1 + d2 * d2;
    for (int m = 1; m < 64; m <<= 1) qv += __shfl_xor(qv, m, 64);
    __shared__ float red2[2];
    if ((tid & 63) == 0) red2[tid >> 6] = qv;
    __syncthreads();
    float var = (red2[0] + red2[1]) * (1.0f / CDIM);
    float rstd = rsqrtf(var + 1e-5f);
    u16* op = outbf + (size_t)row * CDIM;
    op[tid]       = f2b(d0 * rstd * gamma[tid]       + beta[tid]);
    op[tid + 128] = f2b(d1 * rstd * gamma[tid + 128] + beta[tid + 128]);
    op[tid + 256] = f2b(d2 * rstd * gamma[tid + 256] + beta[tid + 256]);
}

// ---------------------------------------------------------------------------
extern "C" void kernel_launch(void* const* d_in, const int* in_sizes, int n_in,
                              void* d_out, int out_size, void* d_ws, size_t ws_size,
                              hipStream_t stream)
{
    (void)in_sizes; (void)n_in; (void)out_size; (void)ws_size;
    const float* x    = (const float*)d_in[0];
    const float* y    = (const float*)d_in[1];
    const float* Wq   = (const float*)d_in[2];
    const float* Wkv  = (const float*)d_in[3];
    const float* EF   = (const float*)d_in[4];
    const float* temp = (const float*)d_in[5];
    const float* gam  = (const float*)d_in[6];
    const float* bet  = (const float*)d_in[7];
    const float* w1   = (const float*)d_in[8];
    const float* b1   = (const float*)d_in[9];
    const float* w2   = (const float*)d_in[10];
    const float* b2   = (const float*)d_in[11];
    float* out = (float*)d_out;

    char* w = (char*)d_ws;
    size_t off = 0;
    auto alloc = [&](size_t nb) { size_t o = off; off += (nb + 255) & ~(size_t)255; return o; };
    u16*   xt_bf = (u16*)(w + alloc((size_t)BDIM * NTOK * CDIM * 2)); // reused as q_bf
    u16*   x_bf  = (u16*)(w + alloc((size_t)BDIM * NTOK * CDIM * 2)); // reused as ln_bf
    u16*   Wqt   = (u16*)(w + alloc((size_t)CDIM * CDIM * 2));
    u16*   EFt   = (u16*)(w + alloc((size_t)PDIM * NTOK * 2));
    u16*   w1t   = (u16*)(w + alloc((size_t)1536 * CDIM * 2));
    u16*   w2t   = (u16*)(w + alloc((size_t)CDIM * 1536 * 2));
    u16*   Wkvt  = (u16*)(w + alloc((size_t)768 * CDIM * 2));
    float* qf    = (float*)(w + alloc((size_t)BDIM * NTOK * CDIM * 4)); // reused as o_scr
    float* gpart = (float*)(w + alloc((size_t)BDIM * NTOK * 1536 * 2)); // union w/ h1bf (50MB)
    u16*   h1bf  = (u16*)gpart;
    u16*   Gt_bf = (u16*)(w + alloc((size_t)BDIM * PDIM * CDIM * 2));
    float* kpvpf = (float*)(w + alloc((size_t)BDIM * PDIM * 2 * CDIM * 4));
    float* pcs   = (float*)(w + alloc((size_t)16 * BDIM * CDIM * 4));
    float* css   = (float*)(w + alloc((size_t)BDIM * CDIM * 4));
    u16*   kps   = (u16*)(w + alloc((size_t)BDIM * NH * PDIM * HDIM * 2));
    u16*   vpb   = (u16*)(w + alloc((size_t)BDIM * NH * HDIM * PDIM * 2));
    u16*   q_bf  = xt_bf;
    float* o_scr = qf;
    u16*   ln_bf = x_bf;

    dim3 tb(32, 8, 1);
    transpose_cast<<<dim3(NTOK / 32, CDIM / 32, BDIM), tb, 0, stream>>>(x, xt_bf, x_bf, CDIM, NTOK);
    transpose_cast<<<dim3(CDIM / 32, CDIM / 32, 1), tb, 0, stream>>>(Wq, Wqt, nullptr, CDIM, CDIM);
    transpose_cast<<<dim3(PDIM / 32, NTOK / 32, 1), tb, 0, stream>>>(EF, EFt, nullptr, NTOK, PDIM);
    transpose_cast<<<dim3(1536 / 32, CDIM / 32, 1), tb, 0, stream>>>(w1, w1t, nullptr, CDIM, 1536);
    transpose_cast<<<dim3(CDIM / 32, 1536 / 32, 1), tb, 0, stream>>>(w2, w2t, nullptr, 1536, CDIM);
    transpose_cast<<<dim3(768 / 32, CDIM / 32, 1), tb, 0, stream>>>(Wkv, Wkvt, nullptr, CDIM, 768);

    // Gt partials: Gt[b][p][c] = sum_n EFt[p,n] * x_bf[b][c][n], split-K 16
    gemm_bt<4><<<dim3(PDIM / 128, CDIM / 128, BDIM * 16), 256, 0, stream>>>(
        EFt, x_bf, PDIM, CDIM, NTOK, 0, (long)CDIM * NTOK, (long)PDIM * CDIM,
        gpart, nullptr, nullptr, nullptr, nullptr);
    gred<<<dim3((BDIM * PDIM * CDIM) / 256, 1, 1), 256, 0, stream>>>(gpart, Gt_bf);

    // q = xt @ Wq -> f32 qf + bf16 q_bf
    gemm_bt<3><<<dim3(NTOK / 128, CDIM / 128, BDIM), 256, 0, stream>>>(
        xt_bf, Wqt, NTOK, CDIM, CDIM, (long)NTOK * CDIM, 0, (long)NTOK * CDIM,
        qf, nullptr, q_bf, nullptr, nullptr);

    colsumsq<<<dim3(CDIM / 128, 16, BDIM), 128, 0, stream>>>(qf, pcs);
    colsumred<<<dim3(6, 1, 1), 256, 0, stream>>>(pcs, css);

    // kpvp_t[b] = Gt_bf[b] @ Wkvt^T : [256, 768] f32
    gemm_bt<0><<<dim3(PDIM / 128, 768 / 128, BDIM), 256, 0, stream>>>(
        Gt_bf, Wkvt, PDIM, 768, CDIM, (long)PDIM * CDIM, 0, (long)PDIM * 768,
        kpvpf, nullptr, nullptr, nullptr, nullptr);

    scalepack2<<<dim3((BDIM * PDIM * CDIM) / 256, 1, 1), 256, 0, stream>>>(
        kpvpf, css, temp, kps, vpb);

    attn_fused<<<dim3(NTOK / 64, NH, BDIM), 256, 0, stream>>>(q_bf, kps, vpb, o_scr);

    ln_kernel<<<dim3(BDIM * NTOK, 1, 1), 128, 0, stream>>>(o_scr, gam, bet, ln_bf);

    // MLP1: gelu(ln @ w1 + b1) -> bf16 [16384,1536]
    gemm_bt<1><<<dim3((BDIM * NTOK) / 128, 1536 / 128, 1), 256, 0, stream>>>(
        ln_bf, w1t, BDIM * NTOK, 1536, CDIM, 0, 0, 0,
        nullptr, b1, h1bf, nullptr, nullptr);
    // MLP2: h1 @ w2 + b2 + y (transposed add) -> f32 out [B,C,N]
    gemm_bt<2><<<dim3((BDIM * NTOK) / 128, CDIM / 128, 1), 256, 0, stream>>>(
        h1bf, w2t, BDIM * NTOK, CDIM, 1536, 0, 0, 0,
        nullptr, b2, nullptr, y, out);
}

// Round 5
// 220.418 us; speedup vs baseline: 1.8251x; 1.0739x over previous
//
#include <hip/hip_runtime.h>

#define NH 8
#define CDIM 384
#define HDIM 48
#define NTOK 4096
#define PDIM 256
#define BDIM 4

typedef unsigned short u16;
typedef unsigned int u32;
typedef __bf16 bf16x8 __attribute__((ext_vector_type(8)));
typedef float f32x4 __attribute__((ext_vector_type(4)));

#define VMFENCE asm volatile("s_waitcnt vmcnt(0)" ::: "memory")

__device__ __forceinline__ u16 f2b(float f) {
    u32 u = __float_as_uint(f);
    u = (u + 0x7fffu + ((u >> 16) & 1u)) >> 16;   // RNE bf16
    return (u16)u;
}
__device__ __forceinline__ float b2f(u16 u) {
    return __uint_as_float(((u32)u) << 16);
}

__device__ __forceinline__ bf16x8 bzero8() {
    bf16x8 v;
#pragma unroll
    for (int i = 0; i < 8; i++) v[i] = (__bf16)0.0f;
    return v;
}

__device__ __forceinline__ void gload16(const u16* g, u16* l) {
    __builtin_amdgcn_global_load_lds(
        (const __attribute__((address_space(1))) void*)g,
        (__attribute__((address_space(3))) void*)l, 16, 0, 0);
}

// tanh-form GELU, max abs err ~3e-4 vs exact erf form
__device__ __forceinline__ float gelu_f(float x) {
    float z = 0.7978845608028654f * (x + 0.044715f * x * x * x);
    float e = __expf(2.0f * z);
    float t = 1.0f - 2.0f / (e + 1.0f);
    return 0.5f * x * (1.0f + t);
}

// ---------------------------------------------------------------------------
// Batched transpose + cast: in f32 [Z,R,Cc] -> outT bf16 [Z,Cc,R]
// optional outC bf16 [Z,R,Cc]. block (32,8)
// ---------------------------------------------------------------------------
__global__ __launch_bounds__(256) void transpose_cast(
    const float* __restrict__ in, u16* __restrict__ outT, u16* __restrict__ outC,
    int R, int Cc)
{
    __shared__ float tile[32][33];
    int r0 = blockIdx.y * 32, c0 = blockIdx.x * 32;
    size_t zoff = (size_t)blockIdx.z * R * Cc;
    const float* inp = in + zoff;
    int tx = threadIdx.x, ty = threadIdx.y;
#pragma unroll
    for (int i = 0; i < 4; i++) {
        int r = r0 + ty + i * 8;
        float v = inp[(size_t)r * Cc + c0 + tx];
        tile[ty + i * 8][tx] = v;
        if (outC) outC[zoff + (size_t)r * Cc + c0 + tx] = f2b(v);
    }
    __syncthreads();
    u16* oT = outT + zoff;
#pragma unroll
    for (int i = 0; i < 4; i++) {
        int c = c0 + ty + i * 8;
        oT[(size_t)c * R + r0 + tx] = f2b(tile[tx][ty + i * 8]);
    }
}

// ---------------------------------------------------------------------------
// GEMM: C[M,N] = A[M,K](bf16,row) @ Bt[N,K](bf16,row)^T, f32 accum.
// Tile BMv x 128 (BMv = HALFM?64:128), BK=32, 4 waves, 16x16x32 MFMA.
// 2-phase double-buffered LDS: issue next-tile global_load_lds before
// current tile's ds_read+MFMA; ONE barrier per K-step, explicit vmcnt(0)
// fence before it so buf[cur^1] is complete when the next step reads it.
// EPI 0: f32 store to Cf (batch offset bz*sC)
// EPI 1: tanh-gelu(x+bias) -> bf16 Cbf
// EPI 2: x + bias[n] + Yin[b,n,tok] -> f32 Out[b,n,tok], float4 over tok
// EPI 4: split-K partials (bz = b*16+s over K-chunk s of 16)
// EPI 5: bf16-only store to Cbf WITH batch offset bz*sC
// ---------------------------------------------------------------------------
template <int EPI, int HALFM>
__global__ __launch_bounds__(256) void gemm_bt(
    const u16* __restrict__ A, const u16* __restrict__ Bt,
    int M, int Nn, int K, long sA, long sB, long sC,
    float* __restrict__ Cf, const float* __restrict__ bias,
    u16* __restrict__ Cbf, const float* __restrict__ Yin, float* __restrict__ Out)
{
    const int BMv = HALFM ? 64 : 128;
    const int MT  = HALFM ? 2 : 4;
    const int BK = 32, LP = 32;
    __shared__ u16 lsA[2][BMv * LP];
    __shared__ u16 lsB[2][128 * LP];
    const int tid = threadIdx.x;
    const int wave = tid >> 6, lane = tid & 63;
    const int lm = lane & 15, lkb = lane >> 4;
    const int bm = blockIdx.x, bn = blockIdx.y, bz = blockIdx.z;
    int bb = bz, ks = 0, ke = K;
    if (EPI == 4) { bb = bz >> 4; ks = (bz & 15) * (K >> 4); ke = ks + (K >> 4); }
    const u16* Ab = A + (size_t)bb * sA;
    const u16* Bb = Bt + (size_t)bb * sB;
    const int wm = (wave >> 1) * (HALFM ? 32 : 64), wn = (wave & 1) * 64;

    f32x4 acc[MT][4];
#pragma unroll
    for (int i = 0; i < MT; i++)
#pragma unroll
        for (int j = 0; j < 4; j++) acc[i][j] = f32x4{0.f, 0.f, 0.f, 0.f};

    auto stage = [&](int k0, int c) {
        if (HALFM) {
            int cb = wave * 64;
            int q = cb + lane;
            int r = q >> 2, ch = q & 3;
            gload16(Ab + (size_t)(bm * BMv + r) * K + k0 + ch * 8, &lsA[c][cb * 8]);
        } else {
#pragma unroll
            for (int j = 0; j < 2; j++) {
                int cb = (j * 4 + wave) * 64;
                int q = cb + lane;
                int r = q >> 2, ch = q & 3;
                gload16(Ab + (size_t)(bm * BMv + r) * K + k0 + ch * 8, &lsA[c][cb * 8]);
            }
        }
#pragma unroll
        for (int j = 0; j < 2; j++) {
            int cb = (j * 4 + wave) * 64;
            int q = cb + lane;
            int r = q >> 2, ch = q & 3;
            gload16(Bb + (size_t)(bn * 128 + r) * K + k0 + ch * 8, &lsB[c][cb * 8]);
        }
    };

    const int nt = (ke - ks) / BK;
    int cur = 0;
    stage(ks, 0);
    VMFENCE;
    __syncthreads();

    for (int t = 0; t < nt; ++t) {
        if (t + 1 < nt) stage(ks + (t + 1) * BK, cur ^ 1);
        bf16x8 af[MT], bfr[4];
#pragma unroll
        for (int m = 0; m < MT; m++)
            af[m] = *(const bf16x8*)&lsA[cur][(wm + m * 16 + lm) * LP + lkb * 8];
#pragma unroll
        for (int n = 0; n < 4; n++)
            bfr[n] = *(const bf16x8*)&lsB[cur][(wn + n * 16 + lm) * LP + lkb * 8];
#pragma unroll
        for (int mi = 0; mi < MT; mi++)
#pragma unroll
            for (int ni = 0; ni < 4; ni++)
                acc[mi][ni] = __builtin_amdgcn_mfma_f32_16x16x32_bf16(
                    af[mi], bfr[ni], acc[mi][ni], 0, 0, 0);
        VMFENCE;
        __syncthreads();
        cur ^= 1;
    }

    if (EPI == 2) {
#pragma unroll
        for (int mi = 0; mi < MT; mi++)
#pragma unroll
            for (int ni = 0; ni < 4; ni++) {
                int m0 = bm * BMv + wm + mi * 16 + lkb * 4;
                int n = bn * 128 + wn + ni * 16 + lm;
                int b = m0 >> 12, tok = m0 & 4095;
                size_t oi = ((size_t)b * CDIM + n) * NTOK + tok;
                float4 yv = *(const float4*)(Yin + oi);
                float bv = bias[n];
                float4 ov;
                ov.x = acc[mi][ni][0] + bv + yv.x;
                ov.y = acc[mi][ni][1] + bv + yv.y;
                ov.z = acc[mi][ni][2] + bv + yv.z;
                ov.w = acc[mi][ni][3] + bv + yv.w;
                *(float4*)(Out + oi) = ov;
            }
    } else {
#pragma unroll
        for (int mi = 0; mi < MT; mi++)
#pragma unroll
            for (int ni = 0; ni < 4; ni++)
#pragma unroll
                for (int r = 0; r < 4; r++) {
                    int m = bm * BMv + wm + mi * 16 + lkb * 4 + r;
                    int n = bn * 128 + wn + ni * 16 + lm;
                    float v = acc[mi][ni][r];
                    if (EPI == 0) {
                        Cf[(size_t)bz * sC + (size_t)m * Nn + n] = v;
                    } else if (EPI == 1) {
                        Cbf[(size_t)m * Nn + n] = f2b(gelu_f(v + bias[n]));
                    } else if (EPI == 4) {
                        Cf[(size_t)bz * sC + (size_t)m * Nn + n] = v;
                    } else {  // EPI == 5: bf16 store with batch offset (bugfix)
                        Cbf[(size_t)bz * sC + (size_t)m * Nn + n] = f2b(v);
                    }
                }
    }
}

// ---------------------------------------------------------------------------
// Reduce 16 split-K slices -> bf16 Gt [B, 256, 384]
// ---------------------------------------------------------------------------
__global__ __launch_bounds__(256) void gred(
    const float* __restrict__ part, u16* __restrict__ Gtb)
{
    int idx = blockIdx.x * 256 + threadIdx.x;      // over B*P*C
    int b = idx / (PDIM * CDIM);
    int e = idx % (PDIM * CDIM);
    float s = 0.f;
#pragma unroll
    for (int j = 0; j < 16; j++)
        s += part[((size_t)(b * 16 + j)) * (PDIM * CDIM) + e];
    Gtb[idx] = f2b(s);
}

// ---------------------------------------------------------------------------
// Column sum-of-squares of q_bf [B,N,C] over N (256-token chunks)
// ---------------------------------------------------------------------------
__global__ __launch_bounds__(128) void colsumsq(
    const u16* __restrict__ q, float* __restrict__ pcs)
{
    int c = blockIdx.x * 128 + threadIdx.x;
    int b = blockIdx.z;
    int chunk = blockIdx.y;
    const u16* qp = q + ((size_t)b * NTOK + chunk * 256) * CDIM + c;
    float s = 0.f;
#pragma unroll 4
    for (int i = 0; i < 256; i++) { float v = b2f(qp[(size_t)i * CDIM]); s += v * v; }
    pcs[(size_t)chunk * (BDIM * CDIM) + b * CDIM + c] = s;
}

__global__ __launch_bounds__(256) void colsumred(
    const float* __restrict__ pcs, float* __restrict__ css)
{
    int idx = blockIdx.x * 256 + threadIdx.x;
    if (idx < BDIM * CDIM) {
        float s = 0.f;
#pragma unroll
        for (int j = 0; j < 16; j++) s += pcs[(size_t)j * (BDIM * CDIM) + idx];
        css[idx] = s;
    }
}

// ---------------------------------------------------------------------------
// From kpvp_t [b, p, 0:384]=kp, [b, p, 384:768]=vp (f32):
// kps [bh, p, d] scaled bf16;  vpb [bh, d, p] bf16
// ---------------------------------------------------------------------------
__global__ __launch_bounds__(256) void scalepack2(
    const float* __restrict__ kpvp, const float* __restrict__ css,
    const float* __restrict__ temp, u16* __restrict__ kps, u16* __restrict__ vpb)
{
    int idx = blockIdx.x * 256 + threadIdx.x;      // over B*P*C
    int c = idx % CDIM;
    int t = idx / CDIM;
    int p = t & 255;
    int b = t >> 8;
    int h = c / HDIM, d = c % HDIM;
    const float* row = kpvp + ((size_t)b * PDIM + p) * (2 * CDIM);
    float kv = row[c];
    float vv = row[CDIM + c];
    float nrm = fmaxf(sqrtf(css[b * CDIM + c]), 1e-12f);
    float sc = temp[h] / nrm;
    int bh = b * NH + h;
    kps[((size_t)bh * PDIM + p) * HDIM + d] = f2b(kv * sc);
    vpb[((size_t)bh * HDIM + d) * PDIM + p] = f2b(vv);
}

// ---------------------------------------------------------------------------
// Fused attention: per (ntile of 64 tokens, h, b).
// ---------------------------------------------------------------------------
__global__ __launch_bounds__(256) void attn_fused(
    const u16* __restrict__ qbf, const u16* __restrict__ kps,
    const u16* __restrict__ vpb, float* __restrict__ o_scr)
{
    __shared__ u16 vp_l[48 * 264];   // [d][p] pad 256->264
    __shared__ u16 un[64 * 264];     // union: kp_l [256][56] then p_l [64][264]
    u16* kp_l = un;
    u16* p_l = un;

    int nt = blockIdx.x, h = blockIdx.y, b = blockIdx.z;
    int tid = threadIdx.x, wave = tid >> 6, lane = tid & 63;
    int lm = lane & 15, lkb = lane >> 4;
    const u16* kpsb = kps + (size_t)(b * NH + h) * PDIM * HDIM;
    const u16* vpbb = vpb + (size_t)(b * NH + h) * HDIM * PDIM;

    for (int i = tid; i < 1536; i += 256) {      // 256 rows x 6 uint4
        int row = i / 6, ch = i % 6;
        *(uint4*)&kp_l[row * 56 + ch * 8] = *(const uint4*)(kpsb + row * 48 + ch * 8);
    }
    for (int i = tid; i < 1536; i += 256) {      // 48 rows x 32 uint4
        int row = i / 32, ch = i % 32;
        *(uint4*)&vp_l[row * 264 + ch * 8] = *(const uint4*)(vpbb + row * 256 + ch * 8);
    }
    __syncthreads();

    int t0 = nt * 64 + wave * 16;
    const u16* qb = qbf + ((size_t)b * NTOK + t0 + lm) * CDIM + h * HDIM;
    bf16x8 a0 = *(const bf16x8*)(qb + lkb * 8);
    bf16x8 a1 = bzero8();
    if (lkb < 2) a1 = *(const bf16x8*)(qb + 32 + lkb * 8);

    f32x4 s[16];
#pragma unroll
    for (int pi = 0; pi < 16; pi++) {
        f32x4 acc = f32x4{0.f, 0.f, 0.f, 0.f};
        bf16x8 b0 = *(const bf16x8*)&kp_l[(pi * 16 + lm) * 56 + lkb * 8];
        acc = __builtin_amdgcn_mfma_f32_16x16x32_bf16(a0, b0, acc, 0, 0, 0);
        bf16x8 b1 = bzero8();
        if (lkb < 2) b1 = *(const bf16x8*)&kp_l[(pi * 16 + lm) * 56 + 32 + lkb * 8];
        acc = __builtin_amdgcn_mfma_f32_16x16x32_bf16(a1, b1, acc, 0, 0, 0);
        s[pi] = acc;
    }
    __syncthreads();   // all QK^T reads of kp_l done before p_l overwrites it

    // softmax over 256 cols
#pragma unroll
    for (int r = 0; r < 4; r++) {
        float mx = s[0][r];
#pragma unroll
        for (int pi = 1; pi < 16; pi++) mx = fmaxf(mx, s[pi][r]);
        for (int m = 1; m < 16; m <<= 1) mx = fmaxf(mx, __shfl_xor(mx, m, 64));
        float e[16];
        float sum = 0.f;
#pragma unroll
        for (int pi = 0; pi < 16; pi++) { e[pi] = __expf(s[pi][r] - mx); sum += e[pi]; }
        for (int m = 1; m < 16; m <<= 1) sum += __shfl_xor(sum, m, 64);
        float inv = 1.0f / sum;
        int tl = wave * 16 + lkb * 4 + r;
#pragma unroll
        for (int pi = 0; pi < 16; pi++)
            p_l[tl * 264 + pi * 16 + lm] = f2b(e[pi] * inv);
    }
    __syncthreads();

    // o = p @ vp^T : per wave 16 tokens x 48 d, K=256
    f32x4 oa[3];
#pragma unroll
    for (int di = 0; di < 3; di++) oa[di] = f32x4{0.f, 0.f, 0.f, 0.f};
#pragma unroll
    for (int ksl = 0; ksl < 8; ksl++) {
        bf16x8 pa = *(const bf16x8*)&p_l[(wave * 16 + lm) * 264 + ksl * 32 + lkb * 8];
#pragma unroll
        for (int di = 0; di < 3; di++) {
            bf16x8 vb = *(const bf16x8*)&vp_l[(di * 16 + lm) * 264 + ksl * 32 + lkb * 8];
            oa[di] = __builtin_amdgcn_mfma_f32_16x16x32_bf16(pa, vb, oa[di], 0, 0, 0);
        }
    }
    size_t obase = (size_t)b * ((size_t)NTOK * CDIM);
#pragma unroll
    for (int di = 0; di < 3; di++) {
        int d = di * 16 + lm;
        int n0 = t0 + lkb * 4;
        float4 ov;
        ov.x = oa[di][0]; ov.y = oa[di][1]; ov.z = oa[di][2]; ov.w = oa[di][3];
        *(float4*)(o_scr + obase + (size_t)(d * NH + h) * NTOK + n0) = ov;
    }
}

// ---------------------------------------------------------------------------
// LayerNorm over rows of 384, write bf16. block 128, one row per block.
// ---------------------------------------------------------------------------
__global__ __launch_bounds__(128) void ln_kernel(
    const float* __restrict__ o, const float* __restrict__ gamma,
    const float* __restrict__ beta, u16* __restrict__ outbf)
{
    int row = blockIdx.x;
    const float* rp = o + (size_t)row * CDIM;
    int tid = threadIdx.x;
    float v0 = rp[tid], v1 = rp[tid + 128], v2 = rp[tid + 256];
    float s = v0 + v1 + v2;
    for (int m = 1; m < 64; m <<= 1) s += __shfl_xor(s, m, 64);
    __shared__ float red[2];
    if ((tid & 63) == 0) red[tid >> 6] = s;
    __syncthreads();
    float mean = (red[0] + red[1]) * (1.0f / CDIM);
    float d0 = v0 - mean, d1 = v1 - mean, d2 = v2 - mean;
    float qv = d0 * d0 + d1 * d1 + d2 * d2;
    for (int m = 1; m < 64; m <<= 1) qv += __shfl_xor(qv, m, 64);
    __shared__ float red2[2];
    if ((tid & 63) == 0) red2[tid >> 6] = qv;
    __syncthreads();
    float var = (red2[0] + red2[1]) * (1.0f / CDIM);
    float rstd = rsqrtf(var + 1e-5f);
    u16* op = outbf + (size_t)row * CDIM;
    op[tid]       = f2b(d0 * rstd * gamma[tid]       + beta[tid]);
    op[tid + 128] = f2b(d1 * rstd * gamma[tid + 128] + beta[tid + 128]);
    op[tid + 256] = f2b(d2 * rstd * gamma[tid + 256] + beta[tid + 256]);
}

// ---------------------------------------------------------------------------
extern "C" void kernel_launch(void* const* d_in, const int* in_sizes, int n_in,
                              void* d_out, int out_size, void* d_ws, size_t ws_size,
                              hipStream_t stream)
{
    (void)in_sizes; (void)n_in; (void)out_size; (void)ws_size;
    const float* x    = (const float*)d_in[0];
    const float* y    = (const float*)d_in[1];
    const float* Wq   = (const float*)d_in[2];
    const float* Wkv  = (const float*)d_in[3];
    const float* EF   = (const float*)d_in[4];
    const float* temp = (const float*)d_in[5];
    const float* gam  = (const float*)d_in[6];
    const float* bet  = (const float*)d_in[7];
    const float* w1   = (const float*)d_in[8];
    const float* b1   = (const float*)d_in[9];
    const float* w2   = (const float*)d_in[10];
    const float* b2   = (const float*)d_in[11];
    float* out = (float*)d_out;

    char* w = (char*)d_ws;
    size_t off = 0;
    auto alloc = [&](size_t nb) { size_t o = off; off += (nb + 255) & ~(size_t)255; return o; };
    u16*   xt_bf = (u16*)(w + alloc((size_t)BDIM * NTOK * CDIM * 2));
    u16*   x_bf  = (u16*)(w + alloc((size_t)BDIM * NTOK * CDIM * 2)); // reused as ln_bf
    u16*   q_bf  = (u16*)(w + alloc((size_t)BDIM * NTOK * CDIM * 2));
    u16*   Wqt   = (u16*)(w + alloc((size_t)CDIM * CDIM * 2));
    u16*   EFt   = (u16*)(w + alloc((size_t)PDIM * NTOK * 2));
    u16*   w1t   = (u16*)(w + alloc((size_t)1536 * CDIM * 2));
    u16*   w2t   = (u16*)(w + alloc((size_t)CDIM * 1536 * 2));
    u16*   Wkvt  = (u16*)(w + alloc((size_t)768 * CDIM * 2));
    float* gpart = (float*)(w + alloc((size_t)BDIM * NTOK * 1536 * 2)); // union w/ h1bf
    u16*   h1bf  = (u16*)gpart;
    u16*   Gt_bf = (u16*)(w + alloc((size_t)BDIM * PDIM * CDIM * 2));
    float* kpvpf = (float*)(w + alloc((size_t)BDIM * PDIM * 2 * CDIM * 4));
    float* pcs   = (float*)(w + alloc((size_t)16 * BDIM * CDIM * 4));
    float* css   = (float*)(w + alloc((size_t)BDIM * CDIM * 4));
    u16*   kps   = (u16*)(w + alloc((size_t)BDIM * NH * PDIM * HDIM * 2));
    u16*   vpb   = (u16*)(w + alloc((size_t)BDIM * NH * HDIM * PDIM * 2));
    float* o_scr = (float*)(w + alloc((size_t)BDIM * NTOK * CDIM * 4));
    u16*   ln_bf = x_bf;

    dim3 tb(32, 8, 1);
    transpose_cast<<<dim3(NTOK / 32, CDIM / 32, BDIM), tb, 0, stream>>>(x, xt_bf, x_bf, CDIM, NTOK);
    transpose_cast<<<dim3(CDIM / 32, CDIM / 32, 1), tb, 0, stream>>>(Wq, Wqt, nullptr, CDIM, CDIM);
    transpose_cast<<<dim3(PDIM / 32, NTOK / 32, 1), tb, 0, stream>>>(EF, EFt, nullptr, NTOK, PDIM);
    transpose_cast<<<dim3(1536 / 32, CDIM / 32, 1), tb, 0, stream>>>(w1, w1t, nullptr, CDIM, 1536);
    transpose_cast<<<dim3(CDIM / 32, 1536 / 32, 1), tb, 0, stream>>>(w2, w2t, nullptr, 1536, CDIM);
    transpose_cast<<<dim3(768 / 32, CDIM / 32, 1), tb, 0, stream>>>(Wkv, Wkvt, nullptr, CDIM, 768);

    // Gt partials: Gt[b][p][c] = sum_n EFt[p,n] * x_bf[b][c][n], split-K 16
    gemm_bt<4, 1><<<dim3(PDIM / 64, CDIM / 128, BDIM * 16), 256, 0, stream>>>(
        EFt, x_bf, PDIM, CDIM, NTOK, 0, (long)CDIM * NTOK, (long)PDIM * CDIM,
        gpart, nullptr, nullptr, nullptr, nullptr);
    gred<<<dim3((BDIM * PDIM * CDIM) / 256, 1, 1), 256, 0, stream>>>(gpart, Gt_bf);

    // q = xt @ Wq -> bf16 q_bf (EPI 5 now applies bz*sC batch offset)
    gemm_bt<5, 1><<<dim3(NTOK / 64, CDIM / 128, BDIM), 256, 0, stream>>>(
        xt_bf, Wqt, NTOK, CDIM, CDIM, (long)NTOK * CDIM, 0, (long)NTOK * CDIM,
        nullptr, nullptr, q_bf, nullptr, nullptr);

    colsumsq<<<dim3(CDIM / 128, 16, BDIM), 128, 0, stream>>>(q_bf, pcs);
    colsumred<<<dim3(6, 1, 1), 256, 0, stream>>>(pcs, css);

    // kpvp_t[b] = Gt_bf[b] @ Wkvt^T : [256, 768] f32
    gemm_bt<0, 1><<<dim3(PDIM / 64, 768 / 128, BDIM), 256, 0, stream>>>(
        Gt_bf, Wkvt, PDIM, 768, CDIM, (long)PDIM * CDIM, 0, (long)PDIM * 768,
        kpvpf, nullptr, nullptr, nullptr, nullptr);

    scalepack2<<<dim3((BDIM * PDIM * CDIM) / 256, 1, 1), 256, 0, stream>>>(
        kpvpf, css, temp, kps, vpb);

    attn_fused<<<dim3(NTOK / 64, NH, BDIM), 256, 0, stream>>>(q_bf, kps, vpb, o_scr);

    ln_kernel<<<dim3(BDIM * NTOK, 1, 1), 128, 0, stream>>>(o_scr, gam, bet, ln_bf);

    // MLP1: gelu(ln @ w1 + b1) -> bf16 [16384,1536]
    gemm_bt<1, 0><<<dim3((BDIM * NTOK) / 128, 1536 / 128, 1), 256, 0, stream>>>(
        ln_bf, w1t, BDIM * NTOK, 1536, CDIM, 0, 0, 0,
        nullptr, b1, h1bf, nullptr, nullptr);
    // MLP2: h1 @ w2 + b2 + y (transposed add) -> f32 out [B,C,N]
    gemm_bt<2, 1><<<dim3((BDIM * NTOK) / 64, CDIM / 128, 1), 256, 0, stream>>>(
        h1bf, w2t, BDIM * NTOK, CDIM, 1536, 0, 0, 0,
        nullptr, b2, nullptr, y, out);
}